// Round 8
// baseline (231.073 us; speedup 1.0000x reference)
//
#include <hip/hip_runtime.h>

// CIN (xDeepFM) fully-fused kernel for MI355X.
// B=4096, F=32, D=32; layer1: K1=1024 -> N=128; layer2: K2=4096 -> N=128.
// GEMM rows=(b,d); A generated in registers: A[(b,d)][h*M+m] = x0[b,h,d]*prev[b,m,d].
// mfma_f32_32x32x16_f16.
// History: R10 pk_mul 4->2 neutral; R11 setprio neutral; R13 pinned
// interleave -10%; R14 (rt=2,ct=2, 4 waves, JIT loads) -26%; R15 (rt=8,ct=1,
// half B traffic, 2x pk_mul) -5% with MfmaUtil UNCHANGED at 63. Reading:
// MfmaUtil is pinned at 63+-1 across 2x VALU, 4x VMEM, and all scheduling
// variants at 2 waves/SIMD; time tracks total per-wave work (serial model
// predicts R15/R10=1.07, observed 1.05). Per-wave streams serialize
// MFMA+VALU+stalls with near-zero cross-wave fill.
// R16: occupancy at CONSTANT B-traffic and prefetch (R14 confounded both:
// 2x volume AND zero prefetch). (rt,ct)=(2,1): acc 32 AGPR -> arch budget
// 96 at 4 waves/SIMD (no spill risk), loads/MFMA=0.5 with depth-4 B ring,
// pk_mul/MFMA=4 (proven ~free). Block = 2b x 128n (4 waves = col slices),
// LDS 20 KB, grid 2048 = 4 blocks/CU x 2 exact passes. launch_bounds(256,4).
// R16 >> R14 would also prove R14's killer was prefetch, not bandwidth.

typedef _Float16 half_t;
typedef _Float16 half4v __attribute__((ext_vector_type(4)));
typedef _Float16 half8 __attribute__((ext_vector_type(8)));
typedef float f32x16 __attribute__((ext_vector_type(16)));

// ---- W pack (both filters, one launch): Wp[s][tg][n][8], k=h*M+mc*16+tg*8+j.
__global__ void prep_w_kernel(const float* __restrict__ W0,
                              const float* __restrict__ W1,
                              half_t* __restrict__ Wp0,
                              half_t* __restrict__ Wp1) {
  int gid = blockIdx.x * 256 + threadIdx.x;  // 320*256 threads
  int n = gid & 127;
  int tg = (gid >> 7) & 1;
  int s = gid >> 8;  // 0..319
  const float* W;
  half_t* Wp;
  int M, sl;
  if (s < 64) { W = W0; Wp = Wp0; M = 32; sl = s; }
  else        { W = W1; Wp = Wp1; M = 128; sl = s - 64; }
  int h = sl & 31, mc = sl >> 5;
  int kbase = h * M + mc * 16 + tg * 8;
  half8 v;
#pragma unroll
  for (int j = 0; j < 8; ++j) v[j] = (half_t)W[(size_t)(kbase + j) * 128 + n];
  *(half8*)(Wp + ((size_t)(sl * 2 + tg) * 128 + n) * 8) = v;
}

// swizzled prevT index: logical (row, m) -> halfs offset. 16B-chunk XOR spread.
__device__ __forceinline__ int pswz(int row, int m) {
  return row * 128 + (((m >> 3) ^ (row & 15)) << 3) + (m & 7);
}

__device__ __forceinline__ f32x16 mfma3216(half8 a, half8 b, f32x16 c) {
  return __builtin_amdgcn_mfma_f32_32x32x16_f16(a, b, c, 0, 0, 0);
}

// One CIN layer, (rt,ct)=(2,1). Per s-step (one h, K=16 slice): 2 A-frags
// (8 pk_mul), 2 MFMAs sharing ONE B frag, then refill that ring slot 4
// s-steps ahead. P[2] = prev rows (bi, d=l31), k-slice mc*16 + hi*8.
// xq: ONE half8 per p covers 4 h x 2 b: xQ[h>>2][d][(h&3)*2 + bi].
template <int MC, bool L1>
__device__ __forceinline__ void layer_loop(const half_t* __restrict__ Wp,
                                           const half_t* __restrict__ psrc,
                                           const half_t* __restrict__ xQb,
                                           int woff, int l31, int hi,
                                           f32x16 acc[2]) {
  half8 P[2];
#pragma unroll
  for (int bi = 0; bi < 2; ++bi)
    P[bi] = L1 ? *(const half8*)&psrc[(bi * 32 + l31) * 40 + hi * 8]
               : *(const half8*)&psrc[pswz(bi * 32 + l31, hi * 8)];

  // B ring, depth 4 (s-steps sb..sb+3), prefetch distance 4.
  half8 Br0 = *(const half8*)(Wp + (size_t)0 * 2048 + woff);
  half8 Br1 = *(const half8*)(Wp + (size_t)1 * 2048 + woff);
  half8 Br2 = *(const half8*)(Wp + (size_t)2 * 2048 + woff);
  half8 Br3 = *(const half8*)(Wp + (size_t)3 * 2048 + woff);

#pragma unroll 1
  for (int mc = 0; mc < MC; ++mc) {
#pragma unroll 1
    for (int p = 0; p < 8; ++p) {
      const int sb = mc * 32 + 4 * p;  // s-steps sb..sb+3 this p
      half8 xq = *(const half8*)(xQb + p * 256);

#define SSTEP(J, BR)                                                       \
  {                                                                        \
    half8 A0 = P[0] * xq[J * 2 + 0];                                       \
    half8 A1 = P[1] * xq[J * 2 + 1];                                       \
    acc[0] = mfma3216(A0, BR, acc[0]);                                     \
    acc[1] = mfma3216(A1, BR, acc[1]);                                     \
    BR = *(const half8*)(Wp +                                              \
                         (size_t)((sb + 4 + J) & (MC * 32 - 1)) * 2048 +   \
                         woff);                                            \
  }
      SSTEP(0, Br0)
      SSTEP(1, Br1)
      SSTEP(2, Br2)
      SSTEP(3, Br3)
#undef SSTEP
    }
    if (mc + 1 < MC) {
      const int mn = (mc + 1) * 16;
#pragma unroll
      for (int bi = 0; bi < 2; ++bi)
        P[bi] = L1 ? *(const half8*)&psrc[(bi * 32 + l31) * 40 + mn + hi * 8]
                   : *(const half8*)&psrc[pswz(bi * 32 + l31, mn + hi * 8)];
    }
  }
}

__global__ __launch_bounds__(256, 4) void cin_fused_kernel(
    const float* __restrict__ x0,    // [4096][32][32] fp32
    const half_t* __restrict__ Wp0,  // 64*2048 halfs
    const half_t* __restrict__ Wp1,  // 256*2048 halfs
    float* __restrict__ out) {       // [4096][256]
  __shared__ half_t xQ[8 * 32 * 8];       // [h>>2][d][(h&3)*2+bi] (4 KB)
  __shared__ half_t prevT[2 * 32 * 128];  // swizzled [bi][d][m] (16 KB); alias xT
  half_t* xT = prevT;                     // [bi*32+d][h], stride 40 halfs

  const int tid = threadIdx.x;
  const int b0 = blockIdx.x * 2;

  // ---- stage x0 -> xQ and xT (2 b = 2048 floats = 512 float4) ----
  const float4* x4 = (const float4*)(x0 + (size_t)b0 * 1024);
#pragma unroll
  for (int r = 0; r < 2; ++r) {
    int q = r * 256 + tid;
    float4 v = x4[q];
    int e4 = q * 4;
    int bi = e4 >> 10, h = (e4 >> 5) & 31, d0 = e4 & 31;
    half4v hv = {(half_t)v.x, (half_t)v.y, (half_t)v.z, (half_t)v.w};
#pragma unroll
    for (int j = 0; j < 4; ++j) {
      xQ[((h >> 2) * 32 + d0 + j) * 8 + (h & 3) * 2 + bi] = hv[j];
      xT[(bi * 32 + d0 + j) * 40 + h] = hv[j];
    }
  }
  __syncthreads();

  const int lane = tid & 63;
  const int l31 = lane & 31;
  const int hi = lane >> 5;
  const int wave = tid >> 6;  // col slice: n in [wave*32, wave*32+32)

  const int woff = hi * 1024 + (wave * 32 + l31) * 8;  // B frag offset
  const half_t* xQb = xQ + l31 * 8;                    // + p*256 per p

  f32x16 acc[2];
#pragma unroll
  for (int bi = 0; bi < 2; ++bi)
#pragma unroll
    for (int r = 0; r < 16; ++r) acc[bi][r] = 0.f;

  // ================= layer 1 =================
  layer_loop<2, true>(Wp0, xT, xQb, woff, l31, hi, acc);

  __syncthreads();  // all waves done reading xT before prevT overwrite

  // ---- epilogue 1: relu, cur1 -> prevT (swizzled), d-sum -> out[:, 0:128] ----
#pragma unroll
  for (int bi = 0; bi < 2; ++bi) {
    float s = 0.f;
#pragma unroll
    for (int r = 0; r < 16; ++r) {
      float v = acc[bi][r];
      v = v > 0.f ? v : 0.f;
      s += v;
      int d = (r & 3) + ((r >> 2) << 3) + hi * 4;  // C/D row map (32x32)
      prevT[pswz(bi * 32 + d, wave * 32 + l31)] = (half_t)v;
      acc[bi][r] = 0.f;
    }
    s += __shfl_down(s, 32);
    if (lane < 32)
      out[(size_t)(b0 + bi) * 256 + wave * 32 + lane] = s;
  }
  __syncthreads();

  // ================= layer 2 =================
  layer_loop<8, false>(Wp1, prevT, xQb, woff, l31, hi, acc);

  // ---- epilogue 2: relu, d-sum -> out[:, 128:256] ----
#pragma unroll
  for (int bi = 0; bi < 2; ++bi) {
    float s = 0.f;
#pragma unroll
    for (int r = 0; r < 16; ++r) {
      float v = acc[bi][r];
      s += v > 0.f ? v : 0.f;
    }
    s += __shfl_down(s, 32);
    if (lane < 32)
      out[(size_t)(b0 + bi) * 256 + 128 + wave * 32 + lane] = s;
  }
}

extern "C" void kernel_launch(void* const* d_in, const int* in_sizes, int n_in,
                              void* d_out, int out_size, void* d_ws,
                              size_t ws_size, hipStream_t stream) {
  const float* x0 = (const float*)d_in[0];  // [4096,32,32]
  const float* w0 = (const float*)d_in[1];  // [1,1024,128]
  const float* w1 = (const float*)d_in[2];  // [1,4096,128]
  float* out = (float*)d_out;               // [4096,256]
  char* ws = (char*)d_ws;

  half_t* Wp0 = (half_t*)(ws);                  // 64*2048 f16 = 256 KB
  half_t* Wp1 = (half_t*)(ws + 64 * 2048 * 2);  // 256*2048 f16 = 1 MB

  hipLaunchKernelGGL(prep_w_kernel, dim3(320), dim3(256), 0, stream, w0, w1,
                     Wp0, Wp1);
  hipLaunchKernelGGL(cin_fused_kernel, dim3(2048), dim3(256), 0, stream, x0,
                     Wp0, Wp1, out);
}

// Round 9
// 201.777 us; speedup vs baseline: 1.1452x; 1.1452x over previous
//
#include <hip/hip_runtime.h>

// CIN (xDeepFM) fully-fused kernel for MI355X.
// B=4096, F=32, D=32; layer1: K1=1024 -> N=128; layer2: K2=4096 -> N=128.
// GEMM rows=(b,d); A generated in registers: A[(b,d)][h*M+m] = x0[b,h,d]*prev[b,m,d].
// mfma_f32_32x32x16_f16.
// Evidence through R16 (per-SIMD totals; MFMA fixed 5120 = 164k pipe-cyc):
//   R10 (VALU 10240, loads 1280, 2 waves) 136us | R15 (20480, 640, 2) 143.5
//   R16 (20480, 2560, 4) 170.5 | R14 (10240, 2560, 4) 172
// -> serial SUM model: time ~ MFMA + VALU + VMEM + stalls, independent of
// wave count (occupancy does NOT buy overlap here). R10 was the sum-min.
// R17: minimize the sum. (rt,ct)=(4,4) at 1 wave/SIMD: acc[4][4]=256 AGPR
// (legal at 1 wave; the 128-AGPR wall at 2 waves is what forced ct=2).
// VALU/MFMA=1 (pk_mul/SIMD halves to 5120), loads/SIMD stays 1280.
// Single-wave blocks (64 thr, 4 b): barriers intra-wave, no cross-wave
// contention. LDS 40KB x 4 blocks/CU = 160KiB exact. B ring depth-2
// s-steps (~1024cyc prefetch); xq prefetched one hp ahead. Grid 1024.
// Also a direct test: can ONE wave saturate the matrix pipe?

typedef _Float16 half_t;
typedef _Float16 half4v __attribute__((ext_vector_type(4)));
typedef _Float16 half8 __attribute__((ext_vector_type(8)));
typedef float f32x16 __attribute__((ext_vector_type(16)));

// ---- W pack (both filters, one launch): Wp[s][tg][n][8], k=h*M+mc*16+tg*8+j.
__global__ void prep_w_kernel(const float* __restrict__ W0,
                              const float* __restrict__ W1,
                              half_t* __restrict__ Wp0,
                              half_t* __restrict__ Wp1) {
  int gid = blockIdx.x * 256 + threadIdx.x;  // 320*256 threads
  int n = gid & 127;
  int tg = (gid >> 7) & 1;
  int s = gid >> 8;  // 0..319
  const float* W;
  half_t* Wp;
  int M, sl;
  if (s < 64) { W = W0; Wp = Wp0; M = 32; sl = s; }
  else        { W = W1; Wp = Wp1; M = 128; sl = s - 64; }
  int h = sl & 31, mc = sl >> 5;
  int kbase = h * M + mc * 16 + tg * 8;
  half8 v;
#pragma unroll
  for (int j = 0; j < 8; ++j) v[j] = (half_t)W[(size_t)(kbase + j) * 128 + n];
  *(half8*)(Wp + ((size_t)(sl * 2 + tg) * 128 + n) * 8) = v;
}

// swizzled prevT index: logical (row, m) -> halfs offset. 16B-chunk XOR spread.
__device__ __forceinline__ int pswz(int row, int m) {
  return row * 128 + (((m >> 3) ^ (row & 15)) << 3) + (m & 7);
}

__device__ __forceinline__ f32x16 mfma3216(half8 a, half8 b, f32x16 c) {
  return __builtin_amdgcn_mfma_f32_32x32x16_f16(a, b, c, 0, 0, 0);
}

// One CIN layer, (rt,ct)=(4,4), one wave. Per s-step (one h): 4 A-frags
// (16 pk_mul), 16 MFMAs (4 bi x 4 col-slices) sharing 4 B frags; refill
// that ring slot 2 s-steps ahead. P[4] = prev rows, k-slice mc*16+hi*8.
// xq: ONE half8 per h-PAIR: xQ[h>>1][d][(h&1)*4+bi], prefetched 1 hp ahead.
template <int MC, bool L1>
__device__ __forceinline__ void layer_loop(const half_t* __restrict__ Wp,
                                           const half_t* __restrict__ psrc,
                                           const half_t* __restrict__ xQb,
                                           int woff, int l31, int hi,
                                           f32x16 acc[4][4]) {
  half8 P[4];
#pragma unroll
  for (int bi = 0; bi < 4; ++bi)
    P[bi] = L1 ? *(const half8*)&psrc[(bi * 32 + l31) * 40 + hi * 8]
               : *(const half8*)&psrc[pswz(bi * 32 + l31, hi * 8)];

  // B ring: slot0 = even s, slot1 = odd s; prefetch distance 2 s-steps.
  half8 Br0[4], Br1[4];
#pragma unroll
  for (int j = 0; j < 4; ++j) {
    Br0[j] = *(const half8*)(Wp + (size_t)0 * 2048 + woff + j * 256);
    Br1[j] = *(const half8*)(Wp + (size_t)1 * 2048 + woff + j * 256);
  }

  half8 xq = *(const half8*)(xQb);  // hp=0

#pragma unroll 1
  for (int mc = 0; mc < MC; ++mc) {
#pragma unroll 1
    for (int hp = 0; hp < 16; ++hp) {
      const int se = mc * 32 + 2 * hp;  // even s-step of this pair
      half8 xqn = *(const half8*)(xQb + (((hp + 1) & 15) * 256));
      // ---- even s-step: h = 2hp, frags xq[0..3], B = Br0 ----
      {
        half8 A0 = P[0] * xq[0], A1 = P[1] * xq[1], A2 = P[2] * xq[2],
              A3 = P[3] * xq[3];
#pragma unroll
        for (int j = 0; j < 4; ++j) acc[0][j] = mfma3216(A0, Br0[j], acc[0][j]);
#pragma unroll
        for (int j = 0; j < 4; ++j) acc[1][j] = mfma3216(A1, Br0[j], acc[1][j]);
#pragma unroll
        for (int j = 0; j < 4; ++j) acc[2][j] = mfma3216(A2, Br0[j], acc[2][j]);
#pragma unroll
        for (int j = 0; j < 4; ++j) acc[3][j] = mfma3216(A3, Br0[j], acc[3][j]);
        const half_t* Wps = Wp + (size_t)((se + 2) & (MC * 32 - 1)) * 2048;
#pragma unroll
        for (int j = 0; j < 4; ++j)
          Br0[j] = *(const half8*)(Wps + woff + j * 256);
      }
      // ---- odd s-step: h = 2hp+1, frags xq[4..7], B = Br1 ----
      {
        half8 A0 = P[0] * xq[4], A1 = P[1] * xq[5], A2 = P[2] * xq[6],
              A3 = P[3] * xq[7];
#pragma unroll
        for (int j = 0; j < 4; ++j) acc[0][j] = mfma3216(A0, Br1[j], acc[0][j]);
#pragma unroll
        for (int j = 0; j < 4; ++j) acc[1][j] = mfma3216(A1, Br1[j], acc[1][j]);
#pragma unroll
        for (int j = 0; j < 4; ++j) acc[2][j] = mfma3216(A2, Br1[j], acc[2][j]);
#pragma unroll
        for (int j = 0; j < 4; ++j) acc[3][j] = mfma3216(A3, Br1[j], acc[3][j]);
        const half_t* Wps = Wp + (size_t)((se + 3) & (MC * 32 - 1)) * 2048;
#pragma unroll
        for (int j = 0; j < 4; ++j)
          Br1[j] = *(const half8*)(Wps + woff + j * 256);
      }
      xq = xqn;
    }
    if (mc + 1 < MC) {
      const int mn = (mc + 1) * 16;
#pragma unroll
      for (int bi = 0; bi < 4; ++bi)
        P[bi] = L1 ? *(const half8*)&psrc[(bi * 32 + l31) * 40 + mn + hi * 8]
                   : *(const half8*)&psrc[pswz(bi * 32 + l31, mn + hi * 8)];
    }
  }
}

__global__ __launch_bounds__(64, 1) void cin_fused_kernel(
    const float* __restrict__ x0,    // [4096][32][32] fp32
    const half_t* __restrict__ Wp0,  // 64*2048 halfs
    const half_t* __restrict__ Wp1,  // 256*2048 halfs
    float* __restrict__ out) {       // [4096][256]
  __shared__ half_t xQ[16 * 32 * 8];      // [h>>1][d][(h&1)*4+bi] (8 KB)
  __shared__ half_t prevT[4 * 32 * 128];  // swizzled [bi][d][m] (32 KB); alias xT
  half_t* xT = prevT;                     // [bi*32+d][h], stride 40 halfs

  const int tid = threadIdx.x;  // 0..63 (one wave)
  const int b0 = blockIdx.x * 4;

  // ---- stage x0 -> xQ and xT (4 b = 4096 floats = 1024 float4) ----
  const float4* x4 = (const float4*)(x0 + (size_t)b0 * 1024);
#pragma unroll
  for (int r = 0; r < 16; ++r) {
    int q = r * 64 + tid;
    float4 v = x4[q];
    int e4 = q * 4;
    int bi = e4 >> 10, h = (e4 >> 5) & 31, d0 = e4 & 31;
    half4v hv = {(half_t)v.x, (half_t)v.y, (half_t)v.z, (half_t)v.w};
#pragma unroll
    for (int j = 0; j < 4; ++j) {
      xQ[((h >> 1) * 32 + d0 + j) * 8 + (h & 1) * 4 + bi] = hv[j];
      xT[(bi * 32 + d0 + j) * 40 + h] = hv[j];
    }
  }
  __syncthreads();

  const int lane = tid;        // single wave
  const int l31 = lane & 31;
  const int hi = lane >> 5;

  const int woff = hi * 1024 + l31 * 8;  // + j*256 per col-slice
  const half_t* xQb = xQ + l31 * 8;      // + hp*256 per h-pair

  f32x16 acc[4][4];
#pragma unroll
  for (int bi = 0; bi < 4; ++bi)
#pragma unroll
    for (int j = 0; j < 4; ++j)
#pragma unroll
      for (int r = 0; r < 16; ++r) acc[bi][j][r] = 0.f;

  // ================= layer 1 =================
  layer_loop<2, true>(Wp0, xT, xQb, woff, l31, hi, acc);

  __syncthreads();  // xT reads done before prevT overwrite (intra-wave)

  // ---- epilogue 1: relu, cur1 -> prevT (swizzled), d-sum -> out[:, 0:128] ----
#pragma unroll
  for (int bi = 0; bi < 4; ++bi) {
#pragma unroll
    for (int j = 0; j < 4; ++j) {
      float s = 0.f;
#pragma unroll
      for (int r = 0; r < 16; ++r) {
        float v = acc[bi][j][r];
        v = v > 0.f ? v : 0.f;
        s += v;
        int d = (r & 3) + ((r >> 2) << 3) + hi * 4;  // C/D row map (32x32)
        prevT[pswz(bi * 32 + d, j * 32 + l31)] = (half_t)v;
        acc[bi][j][r] = 0.f;
      }
      s += __shfl_down(s, 32);
      if (lane < 32)
        out[(size_t)(b0 + bi) * 256 + j * 32 + lane] = s;
    }
  }
  __syncthreads();

  // ================= layer 2 =================
  layer_loop<8, false>(Wp1, prevT, xQb, woff, l31, hi, acc);

  // ---- epilogue 2: relu, d-sum -> out[:, 128:256] ----
#pragma unroll
  for (int bi = 0; bi < 4; ++bi) {
#pragma unroll
    for (int j = 0; j < 4; ++j) {
      float s = 0.f;
#pragma unroll
      for (int r = 0; r < 16; ++r) {
        float v = acc[bi][j][r];
        s += v > 0.f ? v : 0.f;
      }
      s += __shfl_down(s, 32);
      if (lane < 32)
        out[(size_t)(b0 + bi) * 256 + 128 + j * 32 + lane] = s;
    }
  }
}

extern "C" void kernel_launch(void* const* d_in, const int* in_sizes, int n_in,
                              void* d_out, int out_size, void* d_ws,
                              size_t ws_size, hipStream_t stream) {
  const float* x0 = (const float*)d_in[0];  // [4096,32,32]
  const float* w0 = (const float*)d_in[1];  // [1,1024,128]
  const float* w1 = (const float*)d_in[2];  // [1,4096,128]
  float* out = (float*)d_out;               // [4096,256]
  char* ws = (char*)d_ws;

  half_t* Wp0 = (half_t*)(ws);                  // 64*2048 f16 = 256 KB
  half_t* Wp1 = (half_t*)(ws + 64 * 2048 * 2);  // 256*2048 f16 = 1 MB

  hipLaunchKernelGGL(prep_w_kernel, dim3(320), dim3(256), 0, stream, w0, w1,
                     Wp0, Wp1);
  hipLaunchKernelGGL(cin_fused_kernel, dim3(1024), dim3(64), 0, stream, x0,
                     Wp0, Wp1, out);
}

// Round 11
// 194.196 us; speedup vs baseline: 1.1899x; 1.0390x over previous
//
#include <hip/hip_runtime.h>

// CIN (xDeepFM) fully-fused kernel for MI355X.
// B=4096, F=32, D=32; layer1: K1=1024 -> N=128; layer2: K2=4096 -> N=128.
// GEMM rows=(b,d); A generated in registers: A[(b,d)][h*M+m] = x0[b,h,d]*prev[b,m,d].
// mfma_f32_32x32x16_f16.
//
// FINAL (R18 = R10 restored; resubmit after R10-round infra failure -- this
// exact kernel ran twice before: 193.3/196.9us bench, 136/137us fused).
// Session map, per-SIMD totals (MFMA fixed at 5120 = 164k pipe-cyc;
// loads = 5120/rt, pk_mul = 20480/ct):
//   R10 (4,2) loads 1280 pk 10240 2w: 136us  <- optimum
//   R15 (8,1)   640      20480  2w: 143.5 | R17 (4,4) 1280 5120 1w: 148
//   R16 (2,1)  2560      20480  4w: 170.5 | R14 (2,2) 2560 10240 4w: 172
//   R11 setprio / R13 pinned-interleave: null / -10%.
// Reading: 2 waves/SIMD is the optimum (1 wave exposes ~200cy L2 latency on
// B refills, 28% pure idle; 4 waves doubles VMEM and regresses); VALU mix
// is ~free across 2x; VMEM 2560/SIMD is poison. MfmaUtil saturates at 63%,
// equal to the best plain-HIP GEMM precedent (m201: 62.1%). Exceeding it
// needs asm-counted-vmcnt schedules on LDS-staged structures that don't
// graft here (regime-gate: T2/T5 null outside 8-phase; R11/R13 nulls), and
// deeper reg ping-pong exceeds the 256-reg/wave budget (112 arch + 128 acc
// + 64 = spill). Structure-local optimum; NOT claimed as a HW roofline.
// Block = 8 b x 128 n (4 waves: b-quad x col-half), LDS 80 KB, grid 512,
// 2 waves/SIMD (acc 128 AGPR + ~100 arch VGPR).

typedef _Float16 half_t;
typedef _Float16 half4v __attribute__((ext_vector_type(4)));
typedef _Float16 half8 __attribute__((ext_vector_type(8)));
typedef float f32x16 __attribute__((ext_vector_type(16)));

// ---- W pack (both filters, one launch): Wp[s][tg][n][8], k=h*M+mc*16+tg*8+j.
__global__ void prep_w_kernel(const float* __restrict__ W0,
                              const float* __restrict__ W1,
                              half_t* __restrict__ Wp0,
                              half_t* __restrict__ Wp1) {
  int gid = blockIdx.x * 256 + threadIdx.x;  // 320*256 threads
  int n = gid & 127;
  int tg = (gid >> 7) & 1;
  int s = gid >> 8;  // 0..319
  const float* W;
  half_t* Wp;
  int M, sl;
  if (s < 64) { W = W0; Wp = Wp0; M = 32; sl = s; }
  else        { W = W1; Wp = Wp1; M = 128; sl = s - 64; }
  int h = sl & 31, mc = sl >> 5;
  int kbase = h * M + mc * 16 + tg * 8;
  half8 v;
#pragma unroll
  for (int j = 0; j < 8; ++j) v[j] = (half_t)W[(size_t)(kbase + j) * 128 + n];
  *(half8*)(Wp + ((size_t)(sl * 2 + tg) * 128 + n) * 8) = v;
}

// swizzled prevT index: logical (row, m) -> halfs offset. 16B-chunk XOR spread.
__device__ __forceinline__ int pswz(int row, int m) {
  return row * 128 + (((m >> 3) ^ (row & 15)) << 3) + (m & 7);
}

__device__ __forceinline__ f32x16 mfma3216(half8 a, half8 b, f32x16 c) {
  return __builtin_amdgcn_mfma_f32_32x32x16_f16(a, b, c, 0, 0, 0);
}

// One CIN layer: MC m-chunks x 32 h. B/x depth-2 ping-pong (register-renamed,
// zero movs). Per gg: 1 ds_read_b128 (x for 4 rt x 2 h), 2 s-steps; per s:
// one shared A-frag per rt feeds both ct B-frags.
template <int MC, bool L1>
__device__ __forceinline__ void layer_loop(const half_t* __restrict__ Wp,
                                           const half_t* __restrict__ psrc,
                                           const half_t* __restrict__ xQw,
                                           int woff0, int woff1, int rowb,
                                           int l31, int hi, f32x16 acc[4][2]) {
  // ping (even gg) / pong (odd gg) register sets
  half8 B0a0 = *(const half8*)(Wp + 0 * 2048 + woff0);
  half8 B0a1 = *(const half8*)(Wp + 0 * 2048 + woff1);
  half8 B1a0 = *(const half8*)(Wp + 1 * 2048 + woff0);
  half8 B1a1 = *(const half8*)(Wp + 1 * 2048 + woff1);
  half8 B0b0 = *(const half8*)(Wp + 2 * 2048 + woff0);
  half8 B0b1 = *(const half8*)(Wp + 2 * 2048 + woff1);
  half8 B1b0 = *(const half8*)(Wp + 3 * 2048 + woff0);
  half8 B1b1 = *(const half8*)(Wp + 3 * 2048 + woff1);
  half8 xqa = *(const half8*)(xQw);
  half8 xqb = *(const half8*)(xQw + 256);

  half8 P[4];
#pragma unroll
  for (int rt = 0; rt < 4; ++rt)
    P[rt] = L1 ? *(const half8*)&psrc[(rowb + rt * 32 + l31) * 40 + hi * 8]
               : *(const half8*)&psrc[pswz(rowb + rt * 32 + l31, hi * 8)];

#pragma unroll 1
  for (int mc = 0; mc < MC; ++mc) {
#pragma unroll 1
    for (int p = 0; p < 8; ++p) {
      const int g0 = mc * 16 + 2 * p;  // even gg (global)
      // ---- even gg: s = 2g0 (B0?), 2g0+1 (B1?); consume ping ----
#pragma unroll
      for (int rt = 0; rt < 4; ++rt) {
        half8 Af = P[rt] * xqa[rt * 2 + 0];
        acc[rt][0] = mfma3216(Af, B0a0, acc[rt][0]);
        acc[rt][1] = mfma3216(Af, B0a1, acc[rt][1]);
      }
#pragma unroll
      for (int rt = 0; rt < 4; ++rt) {
        half8 Af = P[rt] * xqa[rt * 2 + 1];
        acc[rt][0] = mfma3216(Af, B1a0, acc[rt][0]);
        acc[rt][1] = mfma3216(Af, B1a1, acc[rt][1]);
      }
      {  // refill ping for g0+2
        const int sn = (2 * (g0 + 2)) & (MC * 32 - 1);
        B0a0 = *(const half8*)(Wp + (size_t)sn * 2048 + woff0);
        B0a1 = *(const half8*)(Wp + (size_t)sn * 2048 + woff1);
        B1a0 = *(const half8*)(Wp + (size_t)(sn + 1) * 2048 + woff0);
        B1a1 = *(const half8*)(Wp + (size_t)(sn + 1) * 2048 + woff1);
        xqa = *(const half8*)(xQw + ((2 * p + 2) & 15) * 256);
      }
      // ---- odd gg: consume pong ----
#pragma unroll
      for (int rt = 0; rt < 4; ++rt) {
        half8 Af = P[rt] * xqb[rt * 2 + 0];
        acc[rt][0] = mfma3216(Af, B0b0, acc[rt][0]);
        acc[rt][1] = mfma3216(Af, B0b1, acc[rt][1]);
      }
#pragma unroll
      for (int rt = 0; rt < 4; ++rt) {
        half8 Af = P[rt] * xqb[rt * 2 + 1];
        acc[rt][0] = mfma3216(Af, B1b0, acc[rt][0]);
        acc[rt][1] = mfma3216(Af, B1b1, acc[rt][1]);
      }
      {  // refill pong for g0+3
        const int sn = (2 * (g0 + 3)) & (MC * 32 - 1);
        B0b0 = *(const half8*)(Wp + (size_t)sn * 2048 + woff0);
        B0b1 = *(const half8*)(Wp + (size_t)sn * 2048 + woff1);
        B1b0 = *(const half8*)(Wp + (size_t)(sn + 1) * 2048 + woff0);
        B1b1 = *(const half8*)(Wp + (size_t)(sn + 1) * 2048 + woff1);
        xqb = *(const half8*)(xQw + ((2 * p + 3) & 15) * 256);
      }
    }
    if (mc + 1 < MC) {
      const int mn = (mc + 1) * 16;
#pragma unroll
      for (int rt = 0; rt < 4; ++rt)
        P[rt] = L1 ? *(const half8*)&psrc[(rowb + rt * 32 + l31) * 40 + mn +
                                          hi * 8]
                   : *(const half8*)&psrc[pswz(rowb + rt * 32 + l31,
                                               mn + hi * 8)];
    }
  }
}

__global__ __launch_bounds__(256, 2) void cin_fused_kernel(
    const float* __restrict__ x0,    // [4096][32][32] fp32
    const half_t* __restrict__ Wp0,  // 64*2048 halfs
    const half_t* __restrict__ Wp1,  // 256*2048 halfs
    float* __restrict__ out) {       // [4096][256]
  __shared__ half_t xQ[2 * 16 * 32 * 8];  // [quad][hp][d][rtl*2+(h&1)] (16 KB)
  __shared__ half_t prevT[8 * 32 * 128];  // swizzled [bi][d][m] (64 KB); alias xT
  half_t* xT = prevT;                     // [bi*32+d][h], stride 40 halfs

  const int tid = threadIdx.x;
  const int b0 = blockIdx.x * 8;

  // ---- stage x0 -> xQ and xT (8 b = 8192 floats = 2048 float4) ----
  const float4* x4 = (const float4*)(x0 + (size_t)b0 * 1024);
#pragma unroll
  for (int r = 0; r < 8; ++r) {
    int q = r * 256 + tid;
    float4 v = x4[q];
    int e4 = q * 4;
    int bi = e4 >> 10, h = (e4 >> 5) & 31, d0 = e4 & 31;
    half4v hv = {(half_t)v.x, (half_t)v.y, (half_t)v.z, (half_t)v.w};
    const int quad = bi >> 2, rtl = bi & 3;
#pragma unroll
    for (int j = 0; j < 4; ++j) {
      xQ[quad * 4096 + (h >> 1) * 256 + (d0 + j) * 8 + rtl * 2 + (h & 1)] =
          hv[j];
      xT[(bi * 32 + d0 + j) * 40 + h] = hv[j];
    }
  }
  __syncthreads();

  const int lane = tid & 63;
  const int l31 = lane & 31;
  const int hi = lane >> 5;
  const int wave = tid >> 6;
  const int wr = wave >> 1;  // b-quad: b's wr*4 .. wr*4+3
  const int wc = wave & 1;   // col half: n in [wc*64, wc*64+64)

  const int woff0 = hi * 1024 + (wc * 64 + l31) * 8;       // ct=0 B offset
  const int woff1 = hi * 1024 + (wc * 64 + 32 + l31) * 8;  // ct=1 B offset
  const int rowb = wr * 128;                               // P row base
  const half_t* xQw = xQ + wr * 4096 + l31 * 8;

  f32x16 acc[4][2];
#pragma unroll
  for (int rt = 0; rt < 4; ++rt)
#pragma unroll
    for (int ct = 0; ct < 2; ++ct)
#pragma unroll
      for (int r = 0; r < 16; ++r) acc[rt][ct][r] = 0.f;

  // ================= layer 1 =================
  layer_loop<2, true>(Wp0, xT, xQw, woff0, woff1, rowb, l31, hi, acc);

  __syncthreads();  // all waves done reading xT before prevT overwrite

  // ---- epilogue 1: relu, cur1 -> prevT (swizzled), d-sum -> out[:, 0:128] ----
#pragma unroll
  for (int rt = 0; rt < 4; ++rt) {
#pragma unroll
    for (int ct = 0; ct < 2; ++ct) {
      float s = 0.f;
#pragma unroll
      for (int r = 0; r < 16; ++r) {
        float v = acc[rt][ct][r];
        v = v > 0.f ? v : 0.f;
        s += v;
        int d = (r & 3) + ((r >> 2) << 3) + hi * 4;  // C/D row map (32x32)
        prevT[pswz(rowb + rt * 32 + d, wc * 64 + ct * 32 + l31)] = (half_t)v;
        acc[rt][ct][r] = 0.f;
      }
      s += __shfl_down(s, 32);
      if (lane < 32)
        out[(size_t)(b0 + wr * 4 + rt) * 256 + wc * 64 + ct * 32 + lane] = s;
    }
  }
  __syncthreads();

  // ================= layer 2 =================
  layer_loop<8, false>(Wp1, prevT, xQw, woff0, woff1, rowb, l31, hi, acc);

  // ---- epilogue 2: relu, d-sum -> out[:, 128:256] ----
#pragma unroll
  for (int rt = 0; rt < 4; ++rt) {
#pragma unroll
    for (int ct = 0; ct < 2; ++ct) {
      float s = 0.f;
#pragma unroll
      for (int r = 0; r < 16; ++r) {
        float v = acc[rt][ct][r];
        s += v > 0.f ? v : 0.f;
      }
      s += __shfl_down(s, 32);
      if (lane < 32)
        out[(size_t)(b0 + wr * 4 + rt) * 256 + 128 + wc * 64 + ct * 32 +
            lane] = s;
    }
  }
}

extern "C" void kernel_launch(void* const* d_in, const int* in_sizes, int n_in,
                              void* d_out, int out_size, void* d_ws,
                              size_t ws_size, hipStream_t stream) {
  const float* x0 = (const float*)d_in[0];  // [4096,32,32]
  const float* w0 = (const float*)d_in[1];  // [1,1024,128]
  const float* w1 = (const float*)d_in[2];  // [1,4096,128]
  float* out = (float*)d_out;               // [4096,256]
  char* ws = (char*)d_ws;

  half_t* Wp0 = (half_t*)(ws);                  // 64*2048 f16 = 256 KB
  half_t* Wp1 = (half_t*)(ws + 64 * 2048 * 2);  // 256*2048 f16 = 1 MB

  hipLaunchKernelGGL(prep_w_kernel, dim3(320), dim3(256), 0, stream, w0, w1,
                     Wp0, Wp1);
  hipLaunchKernelGGL(cin_fused_kernel, dim3(512), dim3(256), 0, stream, x0,
                     Wp0, Wp1, out);
}